// Round 9
// baseline (19.797 us; speedup 1.0000x reference)
//
#include <hip/hip_runtime.h>

// Problem geometry (f32):
//   x:   [8, 16, 3, 224, 224]
//   out: [8, 16, 224, 224, 3]  (permute 0,1,4,3,2)
// batch 0: y[0]=x[0]; y[t] = x[t] - 0.4*y[t-1] + 3   (elementwise c,h,w)
// batches 1..6: zeros
// batch 7: z[0]=0; z[t] = 3 - 0.4*z[t-1], broadcast over (w,h,c)
//
// Round 9: per-CU load balance. r3/r6 tile blocks moved 98 KB vs 36 KB fill
// blocks -> most CUs hosted one tile block => ~14% makespan tail (~+1.9us),
// matching the unexplained residual (store-path theories all disproven:
// r3 scatter ~= r6 LDS-vec4 ~= r8 line-exact).
//   - tile = 4h x 32w x 16t = 49.2 KB/block, 392 tiles (bid%5==0; 5 coprime
//     to 8 -> XCD-uniform; every CU gets 1-2 tiles, worst-CU +1.2%)
//   - fill = 2546 fx4 = 40.7 KB/block, 1656 blocks; grid 2048 = 8/CU exact
//   - reads full-line (w=32 -> 128-B aligned chunks), ALL 48 loads before
//     any use (r7 lesson), direct stores, no LDS, no barriers
//   - plain stores everywhere (r5: NT stores regress)

typedef float fx4 __attribute__((ext_vector_type(4)));

#define SP        150528    // 3*224*224 elements per (b,t) slice
#define TT        16
#define CH_STRIDE 50176     // 224*224
#define BSTRIDE   2408448   // 16*SP elements per batch

#define NWT    7            // 224/32 w-tiles
#define NTILES 392          // 56 h-tiles (224/4) x 7 w-tiles
#define TSPREAD 5           // coprime to 8; 391*5 = 1955 < 2048

#define FILL4   4214784     // 7 * 16*SP/4 vec4s (batches 1..7)
#define TSLICE4 37632       // SP/4
#define NBLOCKS 2048
#define NFILL   (NBLOCKS - NTILES)   // 1656
#define RFILL   2546                 // ceil(FILL4/NFILL)

__global__ __launch_bounds__(256) void temporal_fused(
    const float* __restrict__ x, float* __restrict__ out)
{
    const int tid = threadIdx.x;
    const int bid = blockIdx.x;

    const bool is_tile = (bid % TSPREAD == 0) && (bid / TSPREAD) < NTILES;

    if (is_tile) {
        // ------ batch-0 recurrence, tile = 4h x 32w, 128 active threads ----
        if (tid >= 128) return;
        const int tileid = bid / TSPREAD;
        const int h0 = (tileid / NWT) * 4;
        const int w0 = (tileid % NWT) * 32;
        const int dw = tid & 31;       // w offset 0..31 (full 128-B line)
        const int dh = tid >> 5;       // h offset 0..3
        const int rbase = (h0 + dh) * 224 + w0 + dw;

        // ALL 48 loads independent, before any use -> one HBM latency
        float v[TT][3];
        #pragma unroll
        for (int t = 0; t < TT; ++t) {
            #pragma unroll
            for (int c = 0; c < 3; ++c)
                v[t][c] = x[t * SP + c * CH_STRIDE + rbase];
        }

        const int ob = (w0 + dw) * 672 + (h0 + dh) * 3;
        float y0 = v[0][0], y1 = v[0][1], y2 = v[0][2];
        out[ob + 0] = y0;
        out[ob + 1] = y1;
        out[ob + 2] = y2;
        #pragma unroll
        for (int t = 1; t < TT; ++t) {
            y0 = v[t][0] - 0.4f * y0 + 3.0f;
            y1 = v[t][1] - 0.4f * y1 + 3.0f;
            y2 = v[t][2] - 0.4f * y2 + 3.0f;
            const int o = t * SP + ob;
            out[o + 0] = y0;
            out[o + 1] = y1;
            out[o + 2] = y2;
        }
        return;
    }

    // ---------------- fill: batches 1..6 zeros, batch 7 broadcast z[t] ----
    const int tiles_before = min((bid + TSPREAD - 1) / TSPREAD, NTILES);
    const int fidx = bid - tiles_before;          // 0..NFILL-1

    fx4* out4 = reinterpret_cast<fx4*>(out + BSTRIDE); // batch-1 start
    int q   = fidx * RFILL;
    int end = q + RFILL;
    if (end > FILL4) end = FILL4;

    while (q < end) {
        const int slice = q / TSLICE4;            // 0..111 = (batch-1)*16 + t
        int send = (slice + 1) * TSLICE4;
        if (send > end) send = end;
        float zv = 0.0f;
        if ((slice >> 4) == 6) {                  // batch 7
            const int t = slice & 15;
            float z = 0.0f;
            for (int i = 0; i < t; ++i) z = 3.0f - 0.4f * z;
            zv = z;
        }
        fx4 val;
        val.x = zv; val.y = zv; val.z = zv; val.w = zv;
        for (int i = q + tid; i < send; i += 256)
            out4[i] = val;
        q = send;
    }
}

extern "C" void kernel_launch(void* const* d_in, const int* in_sizes, int n_in,
                              void* d_out, int out_size, void* d_ws, size_t ws_size,
                              hipStream_t stream) {
    const float* x = (const float*)d_in[0];
    float* out = (float*)d_out;
    temporal_fused<<<NBLOCKS, 256, 0, stream>>>(x, out);
}